// Round 5
// baseline (762.879 us; speedup 1.0000x reference)
//
#include <hip/hip_runtime.h>
#include <hip/hip_bf16.h>
#include <cmath>

#define NROWS 8192
#define DIM   128
#define KDIM  8192
#define SPLITK 8
#define KCHUNK (KDIM / SPLITK)   // 1024
#define BK    64
#define GITERS (KCHUNK / BK)     // 16
#define BMB   128                // rows per block (4 waves x 32 rows)
#define MTILES (NROWS / BMB)     // 64
#define LDSTRIDE 80              // proj kernel only

typedef __bf16 bf16_t;
typedef __bf16 bf16x8 __attribute__((ext_vector_type(8)));
typedef float  f32x4  __attribute__((ext_vector_type(4)));

// ---------------- fp32 L -> bf16 L (pure streaming convert) -----------------
__global__ void k_cvtL(const float* __restrict__ src, bf16_t* __restrict__ dst) {
    size_t i = ((size_t)blockIdx.x * 256 + threadIdx.x) * 8;
    float4 a = *(const float4*)(src + i);
    float4 b = *(const float4*)(src + i + 4);
    bf16x8 v;
    v[0] = (bf16_t)a.x; v[1] = (bf16_t)a.y; v[2] = (bf16_t)a.z; v[3] = (bf16_t)a.w;
    v[4] = (bf16_t)b.x; v[5] = (bf16_t)b.y; v[6] = (bf16_t)b.z; v[7] = (bf16_t)b.w;
    *(bf16x8*)(dst + i) = v;
}

// ------------- theta: transpose to [k][o][i], scale by c_k, bf16 ------------
__global__ void k_theta(const float* __restrict__ th, bf16_t* __restrict__ out,
                        float c0, float c1, float c2, float c3, float c4) {
    int idx = blockIdx.x * 256 + threadIdx.x;          // 81920 total
    int k = idx >> 14;
    int o = (idx >> 7) & 127;
    int i = idx & 127;
    float c = (k == 0) ? c0 : (k == 1) ? c1 : (k == 2) ? c2 : (k == 3) ? c3 : c4;
    out[idx] = (bf16_t)(c * th[(k << 14) + (i << 7) + o]);
}

// --------- Barrier-free streaming GEMM: partial[s] = A[:,chunk_s] @ Bt^T ----
// A row-major bf16 [8192][8192]; Bt k-major bf16 [128 feat][8192 node].
// No LDS, no __syncthreads: every wave loads its MFMA fragments directly
// from global with fully-coalesced 16B/lane loads (16 rows x 64B per load).
// Wave = 32 rows x 128 cols (2 row-groups x 8 col-groups of 16x16x32 MFMA).
// A is unique per wave (1x HBM traffic); B is redundant but L2-resident.
__global__ void k_gemm(const bf16_t* __restrict__ A, const bf16_t* __restrict__ Bt,
                       float* __restrict__ partial) {
    const int t     = threadIdx.x;
    const int mTile = blockIdx.x & (MTILES - 1);
    const int s     = blockIdx.x >> 6;
    const int wave  = t >> 6, lane = t & 63;
    const int lm = lane & 15, lk = lane >> 4;
    const int row0   = mTile * BMB + wave * 32;   // this wave's first row
    const int k0base = s * KCHUNK;

    f32x4 acc[2][8];
#pragma unroll
    for (int rg = 0; rg < 2; ++rg)
#pragma unroll
        for (int cg = 0; cg < 8; ++cg) acc[rg][cg] = (f32x4)0.0f;

    // lane-resolved base pointers (k-offset added per iter)
    const bf16_t* a0 = A + (size_t)(row0 + lm) * KDIM + lk * 8;
    const bf16_t* a1 = A + (size_t)(row0 + 16 + lm) * KDIM + lk * 8;
    const bf16_t* bb = Bt + (size_t)lm * KDIM + lk * 8;

    auto loadA = [&](int kk, bf16x8 aF[2][2]) {
        const int k0 = k0base + kk * BK;
#pragma unroll
        for (int ko = 0; ko < 2; ++ko) {
            aF[0][ko] = *(const bf16x8*)(a0 + k0 + ko * 32);
            aF[1][ko] = *(const bf16x8*)(a1 + k0 + ko * 32);
        }
    };

    bf16x8 aF[2][2];
    loadA(0, aF);

#pragma unroll 2
    for (int kk = 0; kk < GITERS; ++kk) {
        const int k0 = k0base + kk * BK;
        bf16x8 aN[2][2];
        if (kk + 1 < GITERS) loadA(kk + 1, aN);
#pragma unroll
        for (int ko = 0; ko < 2; ++ko) {
            bf16x8 bq[8];
#pragma unroll
            for (int cg = 0; cg < 8; ++cg)
                bq[cg] = *(const bf16x8*)(bb + (size_t)cg * 16 * KDIM + k0 + ko * 32);
#pragma unroll
            for (int cg = 0; cg < 8; ++cg) {
                acc[0][cg] = __builtin_amdgcn_mfma_f32_16x16x32_bf16(
                    aF[0][ko], bq[cg], acc[0][cg], 0, 0, 0);
                acc[1][cg] = __builtin_amdgcn_mfma_f32_16x16x32_bf16(
                    aF[1][ko], bq[cg], acc[1][cg], 0, 0, 0);
            }
        }
#pragma unroll
        for (int rg = 0; rg < 2; ++rg)
#pragma unroll
            for (int ko = 0; ko < 2; ++ko) aF[rg][ko] = aN[rg][ko];
    }

    float* pOut = partial + (size_t)s * NROWS * DIM;
#pragma unroll
    for (int rg = 0; rg < 2; ++rg)
#pragma unroll
        for (int cg = 0; cg < 8; ++cg)
#pragma unroll
            for (int r = 0; r < 4; ++r) {
                const int row = row0 + rg * 16 + lk * 4 + r;
                const int col = cg * 16 + lm;
                pOut[(size_t)row * DIM + col] = acc[rg][cg][r];
            }
}

// ---- combine: y = sum(partials) [or x]; recurrence; emit fp32/Tbf/Bt -------
// MODE 0: y = src (fp32 x).  MODE 1: y = sum_s partial.  MODE 2: 2*sum - prev.
// tbf: row-major [node][feat]; bt: k-major [feat][node].
template <int MODE>
__global__ void k_combine(const float* __restrict__ src, const float* __restrict__ prev,
                          float* __restrict__ f32dst, bf16_t* __restrict__ tbf,
                          bf16_t* __restrict__ bt) {
    __shared__ bf16_t tl[128 * 24];      // [feat][16 node + pad]
    const size_t S = (size_t)NROWS * DIM;
    const int t  = threadIdx.x;
    const int n0 = blockIdx.x * 16;
    const int nl = t >> 4;               // 0..15 node within tile
    const int dp = (t & 15) * 8;         // 0..120 feature offset
    const int n  = n0 + nl;

    float y[8];
    if (MODE == 0) {
        float4 a = *(const float4*)(src + (size_t)n * DIM + dp);
        float4 b = *(const float4*)(src + (size_t)n * DIM + dp + 4);
        y[0] = a.x; y[1] = a.y; y[2] = a.z; y[3] = a.w;
        y[4] = b.x; y[5] = b.y; y[6] = b.z; y[7] = b.w;
    } else {
#pragma unroll
        for (int j = 0; j < 8; ++j) y[j] = 0.0f;
#pragma unroll
        for (int ss = 0; ss < SPLITK; ++ss) {
            const float* p = src + (size_t)ss * S + (size_t)n * DIM + dp;
            float4 a = *(const float4*)p;
            float4 b = *(const float4*)(p + 4);
            y[0] += a.x; y[1] += a.y; y[2] += a.z; y[3] += a.w;
            y[4] += b.x; y[5] += b.y; y[6] += b.z; y[7] += b.w;
        }
        if (MODE == 2) {
            float4 a = *(const float4*)(prev + (size_t)n * DIM + dp);
            float4 b = *(const float4*)(prev + (size_t)n * DIM + dp + 4);
            y[0] = 2.0f * y[0] - a.x; y[1] = 2.0f * y[1] - a.y;
            y[2] = 2.0f * y[2] - a.z; y[3] = 2.0f * y[3] - a.w;
            y[4] = 2.0f * y[4] - b.x; y[5] = 2.0f * y[5] - b.y;
            y[6] = 2.0f * y[6] - b.z; y[7] = 2.0f * y[7] - b.w;
        }
    }
    if (f32dst) {
        float4 a, b;
        a.x = y[0]; a.y = y[1]; a.z = y[2]; a.w = y[3];
        b.x = y[4]; b.y = y[5]; b.z = y[6]; b.w = y[7];
        *(float4*)(f32dst + (size_t)n * DIM + dp) = a;
        *(float4*)(f32dst + (size_t)n * DIM + dp + 4) = b;
    }
    bf16x8 v;
#pragma unroll
    for (int j = 0; j < 8; ++j) v[j] = (bf16_t)y[j];
    *(bf16x8*)(tbf + (size_t)n * DIM + dp) = v;
    if (bt) {
#pragma unroll
        for (int j = 0; j < 8; ++j) tl[(dp + j) * 24 + nl] = v[j];
        __syncthreads();
        const int d = t >> 1, h = (t & 1) * 8;
        bf16x8 w = *(const bf16x8*)(&tl[d * 24 + h]);
        *(bf16x8*)(bt + (size_t)d * NROWS + n0 + h) = w;
    }
}

// ------- projection: out = sum_seg Tbf[seg] @ thT[seg]^T (c_k pre-folded) ----
__global__ __launch_bounds__(256, 2)
void k_proj(const bf16_t* __restrict__ T, const bf16_t* __restrict__ W,
            float* __restrict__ out) {
    __shared__ __align__(16) bf16_t As[64 * LDSTRIDE];
    __shared__ __align__(16) bf16_t Bs[128 * LDSTRIDE];

    const int t  = threadIdx.x;
    const int mb = blockIdx.x * 64;
    const int wave = t >> 6, lane = t & 63;
    const int wM = (wave & 1) * 32;
    const int wN = (wave >> 1) * 64;
    const int lm = lane & 15, lk = lane >> 4;
    const int arow = t >> 3;
    const int asc  = t & 7;
    const size_t S = (size_t)NROWS * DIM;

    f32x4 acc[2][4];
#pragma unroll
    for (int a = 0; a < 2; ++a)
#pragma unroll
        for (int b = 0; b < 4; ++b) acc[a][b] = (f32x4)0.0f;

    bf16x8 aR[2], bR[4];

    auto loadT = [&](int it) {
        const int seg = it >> 1;
        const int h   = (it & 1) * 64;
#pragma unroll
        for (int rep = 0; rep < 2; ++rep) {
            const int r = rep * 32 + arow;
            aR[rep] = *(const bf16x8*)(T + (size_t)seg * S +
                        (size_t)(mb + r) * DIM + h + asc * 8);
        }
#pragma unroll
        for (int rep = 0; rep < 4; ++rep) {
            const int o = rep * 32 + arow;
            bR[rep] = *(const bf16x8*)(W + seg * 16384 + o * 128 + h + asc * 8);
        }
    };
    auto storeT = [&]() {
#pragma unroll
        for (int rep = 0; rep < 2; ++rep) {
            const int r = rep * 32 + arow;
            *(bf16x8*)(&As[r * LDSTRIDE + asc * 8]) = aR[rep];
        }
#pragma unroll
        for (int rep = 0; rep < 4; ++rep) {
            const int o = rep * 32 + arow;
            *(bf16x8*)(&Bs[o * LDSTRIDE + asc * 8]) = bR[rep];
        }
    };

    loadT(0);
    for (int it = 0; it < 10; ++it) {
        __syncthreads();
        storeT();
        __syncthreads();
        if (it + 1 < 10) loadT(it + 1);
#pragma unroll
        for (int ko = 0; ko < 2; ++ko) {
            bf16x8 af[2], bfr[4];
#pragma unroll
            for (int tm = 0; tm < 2; ++tm)
                af[tm] = *(const bf16x8*)(&As[(wM + tm * 16 + lm) * LDSTRIDE +
                                              (ko * 4 + lk) * 8]);
#pragma unroll
            for (int tn = 0; tn < 4; ++tn)
                bfr[tn] = *(const bf16x8*)(&Bs[(wN + tn * 16 + lm) * LDSTRIDE +
                                               (ko * 4 + lk) * 8]);
#pragma unroll
            for (int tm = 0; tm < 2; ++tm)
#pragma unroll
                for (int tn = 0; tn < 4; ++tn)
                    acc[tm][tn] = __builtin_amdgcn_mfma_f32_16x16x32_bf16(
                        af[tm], bfr[tn], acc[tm][tn], 0, 0, 0);
        }
    }
#pragma unroll
    for (int tm = 0; tm < 2; ++tm)
#pragma unroll
        for (int tn = 0; tn < 4; ++tn)
#pragma unroll
            for (int r = 0; r < 4; ++r) {
                const int row = mb + wM + tm * 16 + lk * 4 + r;
                const int col = wN + tn * 16 + lm;
                out[(size_t)row * DIM + col] = acc[tm][tn][r];
            }
}

extern "C" void kernel_launch(void* const* d_in, const int* in_sizes, int n_in,
                              void* d_out, int out_size, void* d_ws, size_t ws_size,
                              hipStream_t stream) {
    const float* x  = nullptr;
    const float* L  = nullptr;
    const float* th = nullptr;
    for (int i = 0; i < n_in; ++i) {
        if (in_sizes[i] == NROWS * KDIM)       L  = (const float*)d_in[i];
        else if (in_sizes[i] == NROWS * DIM)   x  = (const float*)d_in[i];
        else if (in_sizes[i] == 5 * DIM * DIM) th = (const float*)d_in[i];
    }
    float* out = (float*)d_out;

    const size_t S = (size_t)NROWS * DIM;          // 1048576 elems
    char* ws = (char*)d_ws;
    size_t off = 0;
    auto alloc = [&](size_t bytes) {
        void* p = ws + off;
        off = (off + bytes + 1023) & ~(size_t)1023;
        return p;
    };
    bf16_t* Tbf     = (bf16_t*)alloc(5 * S * 2);        // [5][node][feat]
    bf16_t* Bt      = (bf16_t*)alloc(5 * S * 2);        // [5][feat][node]
    float*  Tf32    = (float*)alloc(2 * S * 4);         // fp32 recurrence state
    bf16_t* thT     = (bf16_t*)alloc(5 * 128 * 128 * 2);
    float*  partial = (float*)alloc((size_t)SPLITK * S * 4);
    bf16_t* Lbf     = (bf16_t*)alloc((size_t)NROWS * KDIM * 2);
    if (off > ws_size) return;

    float c[5];
    for (int k = 0; k < 5; ++k)
        c[k] = (float)((2.0 / 5.0) * exp(-0.5 * cos(M_PI * (k + 0.5) / 5.0)));

    dim3 blk(256);
    k_cvtL<<<32768, blk, 0, stream>>>(L, Lbf);
    k_theta<<<320, blk, 0, stream>>>(th, thT, c[0], c[1], c[2], c[3], c[4]);
    k_combine<0><<<512, blk, 0, stream>>>(x, nullptr, nullptr, Tbf, Bt);

    for (int j = 1; j <= 4; ++j) {
        const bf16_t* Bj = Bt + (size_t)(j - 1) * S;
        k_gemm<<<MTILES * SPLITK, blk, 0, stream>>>(Lbf, Bj, partial);
        bf16_t* tbf = Tbf + (size_t)j * S;
        bf16_t* bt  = (j < 4) ? Bt + (size_t)j * S : nullptr;
        if (j == 1)
            k_combine<1><<<512, blk, 0, stream>>>(partial, nullptr, Tf32 + S, tbf, bt);
        else if (j == 2)
            k_combine<2><<<512, blk, 0, stream>>>(partial, x, Tf32, tbf, bt);
        else if (j == 3)
            k_combine<2><<<512, blk, 0, stream>>>(partial, Tf32 + S, Tf32 + S, tbf, bt);
        else
            k_combine<2><<<512, blk, 0, stream>>>(partial, Tf32, nullptr, tbf, nullptr);
    }
    k_proj<<<128, blk, 0, stream>>>(Tbf, thT, out);
}